// Round 1
// baseline (219.470 us; speedup 1.0000x reference)
//
#include <hip/hip_runtime.h>
#include <float.h>

// Problem constants (from reference):
//   x: [B=32][C=3][L=8192] f32, weight: [O=128][C=3][K=64] f32
//   out[b][o] = -2 * max_t ( conv(b,o,t) - ||w_o||^2/2 - ||win_{b,t}||^2/2 ), t in [0, W)
#define BB 32
#define CC 3
#define LL 8192
#define OO 128
#define KK 64
#define WW (LL - KK + 1)     // 8129
#define CK (CC * KK)         // 192
#define TT 256               // t-tile per block
#define NT 32                // ceil(WW/TT)
#define OBK 64               // o per block
#define WSTR 68              // w_lds leading stride (68%32=4 -> <=8-way store conflict; 68*4B=272B keeps 16B alignment)

__global__ __launch_bounds__(128) void wnorm_kernel(const float* __restrict__ w,
                                                    float* __restrict__ wn) {
    int o = threadIdx.x;               // 128 threads, 1 block
    const float* p = w + o * CK;
    float s = 0.f;
    for (int i = 0; i < CK; ++i) { float v = p[i]; s = fmaf(v, v, s); }
    wn[o] = 0.5f * s;
}

__global__ __launch_bounds__(256) void shapeconv_main(const float* __restrict__ x,
                                                      const float* __restrict__ w,
                                                      const float* __restrict__ wn,
                                                      float* __restrict__ partial) {
    // LDS: 192*68*4 = 52.2 KB weights (transposed) + x tile + sq  => ~57.3 KB -> 2 blocks/CU
    __shared__ __align__(16) float w_lds[CK * WSTR];
    __shared__ __align__(16) float x_lds[3 * 320];
    __shared__ float sq_lds[320];

    const int tt = blockIdx.x;   // t tile 0..31
    const int ob = blockIdx.y;   // o half 0..1
    const int b  = blockIdx.z;   // batch 0..31
    const int tid = threadIdx.x;
    const int t_base = tt * TT;

    // Stage weights transposed: w_lds[ck][oo] = w[(ob*64+oo)*192 + ck]
    const float* wg = w + ob * OBK * CK;
    for (int i = tid; i < OBK * CK; i += 256) {
        int oo = i / CK, ck = i - oo * CK;      // consecutive tid -> consecutive ck (coalesced global)
        w_lds[ck * WSTR + oo] = wg[i];
    }
    // Stage x tile: x_lds[c][j] = x[b][c][t_base+j], j in [0,320), zero-fill OOB
    for (int i = tid; i < 3 * 320; i += 256) {
        int c = i / 320, j = i - c * 320;
        int l = t_base + j;
        x_lds[i] = (l < LL) ? x[(b * 3 + c) * LL + l] : 0.f;
    }
    __syncthreads();

    const int og = tid >> 5;     // 8 o-groups of 8 o
    const int tg = tid & 31;     // 32 t-groups of 8 t
    const int t0 = tg * 8;       // thread's first local t (multiple of 8 -> 32B aligned float4 base)

    float acc[8][8];
    #pragma unroll
    for (int i = 0; i < 8; ++i)
        #pragma unroll
        for (int j = 0; j < 8; ++j) acc[i][j] = 0.f;

    #pragma unroll 1
    for (int c = 0; c < 3; ++c) {
        const float4* xs4 = (const float4*)(x_lds + c * 320 + t0);
        #pragma unroll 1
        for (int kb = 0; kb < 8; ++kb) {
            // x register window: x_local[t0 + kb*8 .. +15]
            float4 X0 = xs4[kb * 2 + 0], X1 = xs4[kb * 2 + 1];
            float4 X2 = xs4[kb * 2 + 2], X3 = xs4[kb * 2 + 3];
            float xv[16] = {X0.x, X0.y, X0.z, X0.w, X1.x, X1.y, X1.z, X1.w,
                            X2.x, X2.y, X2.z, X2.w, X3.x, X3.y, X3.z, X3.w};
            #pragma unroll
            for (int k2 = 0; k2 < 8; ++k2) {
                int ck = c * 64 + kb * 8 + k2;
                const float4* wp = (const float4*)(w_lds + ck * WSTR + og * 8);
                float4 W0 = wp[0], W1 = wp[1];   // broadcast across 32 lanes (og wave-uniform per half)
                float wv[8] = {W0.x, W0.y, W0.z, W0.w, W1.x, W1.y, W1.z, W1.w};
                #pragma unroll
                for (int oi = 0; oi < 8; ++oi)
                    #pragma unroll
                    for (int tj = 0; tj < 8; ++tj)
                        acc[oi][tj] = fmaf(wv[oi], xv[k2 + tj], acc[oi][tj]);
            }
        }
    }

    // sq[j] = sum_c x[c][j]^2 for the tile (need j in [0, 318])
    for (int i = tid; i < 319; i += 256) {
        float s = 0.f;
        #pragma unroll
        for (int c = 0; c < 3; ++c) { float v = x_lds[c * 320 + i]; s = fmaf(v, v, s); }
        sq_lds[i] = s;
    }
    __syncthreads();

    float wnv[8];
    #pragma unroll
    for (int oi = 0; oi < 8; ++oi) wnv[oi] = wn[ob * OBK + og * 8 + oi];

    // sliding window sum of sq over K=64, starting at t0
    float win = 0.f;
    #pragma unroll 1
    for (int k = 0; k < KK; ++k) win += sq_lds[t0 + k];

    float m[8];
    #pragma unroll
    for (int oi = 0; oi < 8; ++oi) m[oi] = -FLT_MAX;

    #pragma unroll
    for (int tj = 0; tj < 8; ++tj) {
        int t = t_base + t0 + tj;
        float hw = 0.5f * win;
        if (t < WW) {
            #pragma unroll
            for (int oi = 0; oi < 8; ++oi) {
                float f = acc[oi][tj] - wnv[oi] - hw;
                m[oi] = fmaxf(m[oi], f);
            }
        }
        if (tj < 7) win += sq_lds[t0 + tj + KK] - sq_lds[t0 + tj];
    }

    // reduce across the 32 t-group lanes sharing an og (xor masks 1..16 stay within 32-lane halves)
    #pragma unroll
    for (int s = 1; s <= 16; s <<= 1)
        #pragma unroll
        for (int oi = 0; oi < 8; ++oi)
            m[oi] = fmaxf(m[oi], __shfl_xor(m[oi], s, 64));

    if (tg == 0) {
        float* pp = partial + ((size_t)(b * 2 + ob) * NT + tt) * OBK + og * 8;
        #pragma unroll
        for (int oi = 0; oi < 8; ++oi) pp[oi] = m[oi];
    }
}

__global__ __launch_bounds__(256) void reduce_kernel(const float* __restrict__ partial,
                                                     float* __restrict__ out) {
    int idx = blockIdx.x * 256 + threadIdx.x;   // 4096 = 32*128
    int b = idx >> 7, o = idx & 127;
    int ob = o >> 6, oo = o & 63;
    const float* pp = partial + (size_t)(b * 2 + ob) * NT * OBK + oo;
    float mx = -FLT_MAX;
    #pragma unroll 4
    for (int tt = 0; tt < NT; ++tt) mx = fmaxf(mx, pp[tt * OBK]);
    out[idx] = -2.f * mx;
}

extern "C" void kernel_launch(void* const* d_in, const int* in_sizes, int n_in,
                              void* d_out, int out_size, void* d_ws, size_t ws_size,
                              hipStream_t stream) {
    const float* x = (const float*)d_in[0];   // [32][3][8192]
    const float* w = (const float*)d_in[1];   // [128][3][64]
    float* out = (float*)d_out;               // [32][128]

    // ws layout: partial [32][2][32][64] f32 (512 KB) | wn [128] f32
    float* partial = (float*)d_ws;
    float* wn = partial + (size_t)BB * 2 * NT * OBK;   // offset 131072 floats

    wnorm_kernel<<<1, 128, 0, stream>>>(w, wn);
    dim3 grid(NT, 2, BB);   // 32 x 2 x 32 = 2048 blocks
    shapeconv_main<<<grid, 256, 0, stream>>>(x, w, wn, partial);
    reduce_kernel<<<16, 256, 0, stream>>>(partial, out);
}

// Round 3
// 97.536 us; speedup vs baseline: 2.2501x; 2.2501x over previous
//
#include <hip/hip_runtime.h>
#include <float.h>

// x: [B=32][C=3][L=8192] f32, weight: [O=128][C=3][K=64] f32
// out[b][o] = -2 * max_t ( conv(b,o,t) - ||w_o||^2/2 - ||win_{b,t}||^2/2 ), t in [0, 8129)
#define BB 32
#define LL 8192
#define OO 128
#define KK 64
#define WW (LL - KK + 1)   // 8129

typedef __attribute__((ext_vector_type(8))) short short8;
typedef __attribute__((ext_vector_type(4))) float f32x4;

union AB { int4 i4; int i[4]; short8 v; };

static __device__ __forceinline__ unsigned int f2bf(float f) {
    unsigned int u = __builtin_bit_cast(unsigned int, f);
    return (u + 0x7FFFu + ((u >> 16) & 1u)) >> 16;   // RNE
}

// Single fused kernel. Grid (16 tc, 32 b), 256 threads = 4 waves.
// Block covers t in [tc*512, tc*512+512) as 2 chunks of 256.
// Wave wv covers o in [32wv, 32wv+32) (2 o-tiles of 16).
// MFMA t-map: t = T0 + r + 16n, r in [0,16), n = lane&15  -> full 256-t coverage
// (round-2 bug: r<8 with +8n covered only 128 of 256 t).
__global__ __launch_bounds__(256, 2) void shapeconv_fused(const float* __restrict__ x,
                                                          const float* __restrict__ w,
                                                          float* __restrict__ out) {
    __shared__ __align__(16) unsigned short x_lds[3 * 320];   // bf16 tile
    __shared__ float sq_lds[320];
    __shared__ float P_lds[40];          // 8-element partial sums of sq
    __shared__ float win_lds[272];       // padded index t + (t>>4)
    __shared__ float wn_lds[128];

    const int tc = blockIdx.x;
    const int b  = blockIdx.y;
    const int tid = threadIdx.x;
    const int wv = tid >> 6;
    const int lane = tid & 63;
    const int n  = lane & 15;
    const int qp = lane >> 4;

    // ---- preamble: load W fp32 -> bf16 A-fragments in-register; wn partials ----
    // A[m=lane&15=n][k=qp*8+j]; o = 32wv + 16ot + n; ck = 64*(ks>>1) + 32*(ks&1) + 8qp + j
    AB afr[2][6];
    float wns[2] = {0.f, 0.f};
    #pragma unroll
    for (int ot = 0; ot < 2; ++ot) {
        int o = wv * 32 + ot * 16 + n;
        #pragma unroll
        for (int ks = 0; ks < 6; ++ks) {
            const float4* p = (const float4*)(w + o * 192 + (ks >> 1) * 64 + (ks & 1) * 32 + qp * 8);
            float4 A0 = p[0], A1 = p[1];
            float vv[8] = {A0.x, A0.y, A0.z, A0.w, A1.x, A1.y, A1.z, A1.w};
            #pragma unroll
            for (int j = 0; j < 8; ++j) wns[ot] = fmaf(vv[j], vv[j], wns[ot]);
            afr[ot][ks].i[0] = (int)(f2bf(vv[0]) | (f2bf(vv[1]) << 16));
            afr[ot][ks].i[1] = (int)(f2bf(vv[2]) | (f2bf(vv[3]) << 16));
            afr[ot][ks].i[2] = (int)(f2bf(vv[4]) | (f2bf(vv[5]) << 16));
            afr[ot][ks].i[3] = (int)(f2bf(vv[6]) | (f2bf(vv[7]) << 16));
        }
    }
    #pragma unroll
    for (int ot = 0; ot < 2; ++ot) {            // reduce over qp (lane bits 4,5)
        wns[ot] += __shfl_xor(wns[ot], 16, 64);
        wns[ot] += __shfl_xor(wns[ot], 32, 64);
    }
    if (qp == 0) {
        wn_lds[wv * 32 + n]      = 0.5f * wns[0];
        wn_lds[wv * 32 + 16 + n] = 0.5f * wns[1];
    }

    float m[2][4];
    #pragma unroll
    for (int ot = 0; ot < 2; ++ot)
        #pragma unroll
        for (int rg = 0; rg < 4; ++rg) m[ot][rg] = -FLT_MAX;

    for (int it = 0; it < 2; ++it) {
        const int T0 = (tc * 2 + it) * 256;
        __syncthreads();   // (A) protects LDS from prior chunk readers; makes wn_lds visible

        // stage x tile (bf16) ...
        for (int i = tid; i < 960; i += 256) {
            int c = i / 320, j = i - c * 320;
            int l = T0 + j;
            float v = (l < LL) ? x[(b * 3 + c) * LL + l] : 0.f;
            x_lds[i] = (unsigned short)f2bf(v);
        }
        // ... sq[j] (fp32, from original x; L1-hot reload) ...
        for (int j = tid; j < 320; j += 256) {
            int l = T0 + j;
            float s = 0.f;
            if (l < LL) {
                #pragma unroll
                for (int c = 0; c < 3; ++c) {
                    float v = x[(b * 3 + c) * LL + l];
                    s = fmaf(v, v, s);
                }
            }
            sq_lds[j] = s;
        }
        // ... and 8-wide partials P[i] = sum_{k<8} sq[8i+k] straight from global (no sq dep)
        if (tid < 40) {
            float s = 0.f;
            #pragma unroll
            for (int k = 0; k < 8; ++k) {
                int l = T0 + tid * 8 + k;
                if (l < LL) {
                    #pragma unroll
                    for (int c = 0; c < 3; ++c) {
                        float v = x[(b * 3 + c) * LL + l];
                        s = fmaf(v, v, s);
                    }
                }
            }
            P_lds[tid] = s;
        }
        __syncthreads();   // (B)

        // win[t] = 0.5 * sum_{k<64} sq[t+k] via P8 partials: t = 8a + bb
        {
            int a = tid >> 3, bb2 = tid & 7;
            float s = 0.f;
            #pragma unroll
            for (int i = 1; i <= 7; ++i) s += P_lds[a + i];
            #pragma unroll
            for (int k = 0; k < 8; ++k)
                s += (k >= bb2) ? sq_lds[8 * a + k] : sq_lds[8 * a + 64 + k];
            int pi = tid + (tid >> 4);
            win_lds[pi] = (T0 + tid < WW) ? 0.5f * s : 1e30f;   // invalid t masked
        }
        __syncthreads();   // (C) win_lds + wn_lds ready

        // init acc with -(wn + win): epilogue becomes pure register max
        float negwn[2][4];
        #pragma unroll
        for (int ot = 0; ot < 2; ++ot)
            #pragma unroll
            for (int rg = 0; rg < 4; ++rg)
                negwn[ot][rg] = -wn_lds[wv * 32 + ot * 16 + 4 * qp + rg];

        float wl[16];
        #pragma unroll
        for (int r = 0; r < 16; ++r) {
            int tl = r + 16 * n;
            wl[r] = win_lds[tl + (tl >> 4)];
        }
        f32x4 acc[2][16];
        #pragma unroll
        for (int ot = 0; ot < 2; ++ot)
            #pragma unroll
            for (int r = 0; r < 16; ++r)
                #pragma unroll
                for (int rg = 0; rg < 4; ++rg)
                    acc[ot][r][rg] = negwn[ot][rg] - wl[r];

        // K-loop: 6 ks x 16 r x 2 ot = 192 MFMAs/wave
        const char* xb = (const char*)x_lds;
        #pragma unroll
        for (int ks = 0; ks < 6; ++ks) {
            int e0b = 640 * (ks >> 1) + 64 * (ks & 1) + 32 * n + 16 * qp;   // 16B aligned
            int4 Ea = *(const int4*)(xb + e0b);
            int4 Eb = *(const int4*)(xb + e0b + 16);
            int4 Ec = *(const int4*)(xb + e0b + 32);
            int D[12] = {Ea.x, Ea.y, Ea.z, Ea.w, Eb.x, Eb.y, Eb.z, Eb.w, Ec.x, Ec.y, Ec.z, Ec.w};
            #pragma unroll
            for (int r = 0; r < 16; ++r) {
                AB bf;
                int s = r >> 1;
                if ((r & 1) == 0) {
                    bf.i[0] = D[s]; bf.i[1] = D[s + 1]; bf.i[2] = D[s + 2]; bf.i[3] = D[s + 3];
                } else {
                    #pragma unroll
                    for (int d = 0; d < 4; ++d)
                        bf.i[d] = (int)(((unsigned)D[s + d] >> 16) | ((unsigned)D[s + d + 1] << 16));
                }
                acc[0][r] = __builtin_amdgcn_mfma_f32_16x16x32_bf16(afr[0][ks].v, bf.v, acc[0][r], 0, 0, 0);
                acc[1][r] = __builtin_amdgcn_mfma_f32_16x16x32_bf16(afr[1][ks].v, bf.v, acc[1][r], 0, 0, 0);
            }
        }

        // epilogue: pure register max (norms already folded into init)
        #pragma unroll
        for (int ot = 0; ot < 2; ++ot)
            #pragma unroll
            for (int r = 0; r < 16; ++r)
                #pragma unroll
                for (int rg = 0; rg < 4; ++rg)
                    m[ot][rg] = fmaxf(m[ot][rg], acc[ot][r][rg]);
    }

    // cross-lane max over n (lane bits 0..3); qp rows distinct
    #pragma unroll
    for (int s = 1; s <= 8; s <<= 1)
        #pragma unroll
        for (int ot = 0; ot < 2; ++ot)
            #pragma unroll
            for (int rg = 0; rg < 4; ++rg)
                m[ot][rg] = fmaxf(m[ot][rg], __shfl_xor(m[ot][rg], s, 64));

    // out[b][o] = min over blocks of (-2*m); CAS float-min (d_out pre-set to +3.4e38)
    if (n == 0) {
        #pragma unroll
        for (int ot = 0; ot < 2; ++ot)
            #pragma unroll
            for (int rg = 0; rg < 4; ++rg) {
                int o = wv * 32 + ot * 16 + 4 * qp + rg;
                float v = -2.f * m[ot][rg];
                int* p = (int*)(out + b * OO + o);
                int cur = __hip_atomic_load(p, __ATOMIC_RELAXED, __HIP_MEMORY_SCOPE_AGENT);
                while (v < __int_as_float(cur)) {
                    int prev = atomicCAS(p, cur, __float_as_int(v));
                    if (prev == cur) break;
                    cur = prev;
                }
            }
    }
}

extern "C" void kernel_launch(void* const* d_in, const int* in_sizes, int n_in,
                              void* d_out, int out_size, void* d_ws, size_t ws_size,
                              hipStream_t stream) {
    const float* x = (const float*)d_in[0];   // [32][3][8192]
    const float* w = (const float*)d_in[1];   // [128][3][64]
    float* out = (float*)d_out;               // [32][128]

    // init d_out to 0x7F7F7F7F = 3.39e38 so CAS-min works from a known high value
    hipMemsetAsync(out, 0x7F, (size_t)out_size * sizeof(float), stream);
    dim3 grid(16, BB);                        // 512 blocks = 2/CU
    shapeconv_fused<<<grid, 256, 0, stream>>>(x, w, out);
}

// Round 4
// 82.227 us; speedup vs baseline: 2.6691x; 1.1862x over previous
//
#include <hip/hip_runtime.h>
#include <float.h>

// x: [B=32][C=3][L=8192] f32, weight: [O=128][C=3][K=64] f32
// out[b][o] = -2 * max_t ( conv(b,o,t) - ||w_o||^2/2 - ||win_{b,t}||^2/2 ), t in [0, 8129)
#define BB 32
#define LL 8192
#define OO 128
#define KK 64
#define WW (LL - KK + 1)   // 8129
#define TC 32              // t-chunks of 256

typedef __attribute__((ext_vector_type(8))) short short8;
typedef __attribute__((ext_vector_type(4))) float f32x4;

union AB { int4 i4; int i[4]; short8 v; };

static __device__ __forceinline__ unsigned int f2bf(float f) {
    unsigned int u = __builtin_bit_cast(unsigned int, f);
    return (u + 0x7FFFu + ((u >> 16) & 1u)) >> 16;   // RNE
}

// Grid (32 tc, 2 ob, 32 b) = 2048 blocks, 256 threads = 4 waves.
// Block: o in [64ob, 64ob+64), t in [256tc, 256tc+256).
// Wave (wo = wv&1, wt = wv>>1): o-half [64ob+32wo, +32) (2 o-tiles of 16),
// t-half t = 256tc + 128wt + r + 8n (r<8, n=lane&15) -> 128 t per wave.
// Registers: acc[2][8] = 64 + ~45 VGPR -> fits 128 total -> 4 waves/SIMD.
// Weights live in LDS (bf16, row stride 200 elems: 400B -> 2-way-free banks).
__global__ __launch_bounds__(256, 4) void shapeconv_main(const float* __restrict__ x,
                                                         const float* __restrict__ w,
                                                         float* __restrict__ partial) {
    __shared__ __align__(16) unsigned short w_lds[64 * 200];   // 25600 B
    __shared__ __align__(16) unsigned short x_lds[3 * 320];    // bf16 tile
    __shared__ float sq_lds[320];
    __shared__ float P_lds[40];
    __shared__ float win_lds[272];     // padded idx t + (t>>4)
    __shared__ float wn_lds[64];
    __shared__ float mred[64];

    const int tc = blockIdx.x;
    const int ob = blockIdx.y;
    const int b  = blockIdx.z;
    const int tid = threadIdx.x;
    const int wv = tid >> 6;
    const int lane = tid & 63;
    const int wo = wv & 1, wt = wv >> 1;
    const int n  = lane & 15;
    const int qp = lane >> 4;
    const int T0 = tc * 256;

    // ---- stage W -> w_lds bf16 (row stride 200), wn[o] = ||w_o||^2/2 (fp32) ----
    {
        int o = tid >> 2, q = tid & 3;              // o<64, q: 48-elem quarter
        const float4* p = (const float4*)(w + (ob * 64 + o) * 192 + q * 48);
        unsigned short* dst = w_lds + o * 200 + q * 48;   // 96B offset: 16B aligned
        float s = 0.f;
        #pragma unroll
        for (int i = 0; i < 6; ++i) {               // 6 x (2 float4 -> 1 ds_write_b128)
            float4 v0 = p[2 * i], v1 = p[2 * i + 1];
            s = fmaf(v0.x, v0.x, s); s = fmaf(v0.y, v0.y, s);
            s = fmaf(v0.z, v0.z, s); s = fmaf(v0.w, v0.w, s);
            s = fmaf(v1.x, v1.x, s); s = fmaf(v1.y, v1.y, s);
            s = fmaf(v1.z, v1.z, s); s = fmaf(v1.w, v1.w, s);
            int4 pk;
            pk.x = (int)(f2bf(v0.x) | (f2bf(v0.y) << 16));
            pk.y = (int)(f2bf(v0.z) | (f2bf(v0.w) << 16));
            pk.z = (int)(f2bf(v1.x) | (f2bf(v1.y) << 16));
            pk.w = (int)(f2bf(v1.z) | (f2bf(v1.w) << 16));
            *(int4*)(dst + 8 * i) = pk;
        }
        s += __shfl_xor(s, 1, 64);
        s += __shfl_xor(s, 2, 64);
        if (q == 0) wn_lds[o] = 0.5f * s;
    }

    // ---- stage x tile (bf16), sq (fp32), P8 partials — all straight from global ----
    {
        int i = tid;                                 // 240 float4 cover 3x320
        if (i < 240) {
            int c = i / 80, j4 = i - c * 80;
            int l = T0 + j4 * 4;
            float4 v = make_float4(0.f, 0.f, 0.f, 0.f);
            if (l < LL) v = *(const float4*)(x + (b * 3 + c) * LL + l);
            uint2 pk;
            pk.x = f2bf(v.x) | (f2bf(v.y) << 16);
            pk.y = f2bf(v.z) | (f2bf(v.w) << 16);
            *(uint2*)(x_lds + c * 320 + j4 * 4) = pk;
        }
    }
    for (int j = tid; j < 320; j += 256) {
        int l = T0 + j;
        float s = 0.f;
        if (l < LL) {
            #pragma unroll
            for (int c = 0; c < 3; ++c) {
                float v = x[(b * 3 + c) * LL + l];   // L1-hot (same lines as stage)
                s = fmaf(v, v, s);
            }
        }
        sq_lds[j] = s;
    }
    if (tid < 40) {
        float s = 0.f;
        #pragma unroll
        for (int k = 0; k < 8; ++k) {
            int l = T0 + tid * 8 + k;
            if (l < LL) {
                #pragma unroll
                for (int c = 0; c < 3; ++c) {
                    float v = x[(b * 3 + c) * LL + l];
                    s = fmaf(v, v, s);
                }
            }
        }
        P_lds[tid] = s;
    }
    __syncthreads();   // B1: w_lds, x_lds, sq_lds, P_lds ready

    // win[t] = 0.5 * sum_{k<64} sq[t+k] via P8; invalid t -> +1e30 (masks max)
    {
        int a = tid >> 3, bb2 = tid & 7;
        float s = 0.f;
        #pragma unroll
        for (int i = 1; i <= 7; ++i) s += P_lds[a + i];
        #pragma unroll
        for (int k = 0; k < 8; ++k)
            s += (k >= bb2) ? sq_lds[8 * a + k] : sq_lds[8 * a + 64 + k];
        int pi = tid + (tid >> 4);
        win_lds[pi] = (T0 + tid < WW) ? 0.5f * s : 1e30f;
    }
    __syncthreads();   // B2: win_lds, wn_lds ready

    // ---- acc init with -(wn + win): epilogue becomes pure register max ----
    f32x4 acc[2][8];
    {
        float wl[8];
        #pragma unroll
        for (int r = 0; r < 8; ++r) {
            int tl = 128 * wt + r + 8 * n;
            wl[r] = win_lds[tl + (tl >> 4)];
        }
        #pragma unroll
        for (int ot = 0; ot < 2; ++ot)
            #pragma unroll
            for (int rg = 0; rg < 4; ++rg) {
                float nw = wn_lds[32 * wo + 16 * ot + 4 * qp + rg];
                #pragma unroll
                for (int r = 0; r < 8; ++r)
                    acc[ot][r][rg] = -nw - wl[r];
            }
    }

    // ---- K-loop: 6 ks x 8 r x 2 ot = 96 MFMAs/wave ----
    const char* xb = (const char*)x_lds;
    const char* wb = (const char*)w_lds;
    #pragma unroll
    for (int ks = 0; ks < 6; ++ks) {
        int c = ks >> 1, h = ks & 1;
        // B window: 15 elems at base (16B aligned): elem = c*320 + 128wt + 32h + 8(n+qp) + (r+j)
        int e0b = c * 640 + 256 * wt + 64 * h + 16 * (n + qp);
        int4 Ea = *(const int4*)(xb + e0b);
        int4 Eb = *(const int4*)(xb + e0b + 16);
        int D[8] = {Ea.x, Ea.y, Ea.z, Ea.w, Eb.x, Eb.y, Eb.z, Eb.w};
        // A frags from LDS: row = 32wo + 16ot + n, k-offset 128c + 64h + 16qp (bytes)
        AB a0, a1;
        int ab0 = (32 * wo + n) * 400 + 128 * c + 64 * h + 16 * qp;
        a0.i4 = *(const int4*)(wb + ab0);
        a1.i4 = *(const int4*)(wb + ab0 + 16 * 400);
        #pragma unroll
        for (int r = 0; r < 8; ++r) {
            AB bf;
            int s = r >> 1;
            if ((r & 1) == 0) {
                bf.i[0] = D[s]; bf.i[1] = D[s + 1]; bf.i[2] = D[s + 2]; bf.i[3] = D[s + 3];
            } else {
                #pragma unroll
                for (int d = 0; d < 4; ++d)
                    bf.i[d] = (int)(((unsigned)D[s + d] >> 16) | ((unsigned)D[s + d + 1] << 16));
            }
            acc[0][r] = __builtin_amdgcn_mfma_f32_16x16x32_bf16(a0.v, bf.v, acc[0][r], 0, 0, 0);
            acc[1][r] = __builtin_amdgcn_mfma_f32_16x16x32_bf16(a1.v, bf.v, acc[1][r], 0, 0, 0);
        }
    }

    // ---- epilogue: register max, cross-lane over n, wt-pair combine, dump ----
    float m2[2][4];
    #pragma unroll
    for (int ot = 0; ot < 2; ++ot)
        #pragma unroll
        for (int rg = 0; rg < 4; ++rg) {
            float mm = acc[ot][0][rg];
            #pragma unroll
            for (int r = 1; r < 8; ++r) mm = fmaxf(mm, acc[ot][r][rg]);
            m2[ot][rg] = mm;
        }
    #pragma unroll
    for (int s = 1; s <= 8; s <<= 1)
        #pragma unroll
        for (int ot = 0; ot < 2; ++ot)
            #pragma unroll
            for (int rg = 0; rg < 4; ++rg)
                m2[ot][rg] = fmaxf(m2[ot][rg], __shfl_xor(m2[ot][rg], s, 64));

    if (wt == 1 && n == 0) {
        #pragma unroll
        for (int ot = 0; ot < 2; ++ot)
            #pragma unroll
            for (int rg = 0; rg < 4; ++rg)
                mred[32 * wo + 16 * ot + 4 * qp + rg] = m2[ot][rg];
    }
    __syncthreads();   // B3
    if (wt == 0 && n == 0) {
        #pragma unroll
        for (int ot = 0; ot < 2; ++ot)
            #pragma unroll
            for (int rg = 0; rg < 4; ++rg) {
                int oi = 32 * wo + 16 * ot + 4 * qp + rg;
                float v = fmaxf(m2[ot][rg], mred[oi]);
                partial[((size_t)(b * TC + tc) * 2 + ob) * 64 + oi] = v;
            }
    }
}

// max over the 32 t-chunks, scale by -2
__global__ __launch_bounds__(256) void reduce_kernel(const float* __restrict__ partial,
                                                     float* __restrict__ out) {
    int idx = blockIdx.x * 256 + threadIdx.x;   // 4096 = 32*128
    int b = idx >> 7, o = idx & 127;
    const float* pp = partial + ((size_t)b * TC * 2 + (o >> 6)) * 64 + (o & 63);
    float mx = -FLT_MAX;
    #pragma unroll 8
    for (int tcc = 0; tcc < TC; ++tcc) mx = fmaxf(mx, pp[(size_t)tcc * 128]);
    out[idx] = -2.f * mx;
}

extern "C" void kernel_launch(void* const* d_in, const int* in_sizes, int n_in,
                              void* d_out, int out_size, void* d_ws, size_t ws_size,
                              hipStream_t stream) {
    const float* x = (const float*)d_in[0];   // [32][3][8192]
    const float* w = (const float*)d_in[1];   // [128][3][64]
    float* out = (float*)d_out;               // [32][128]
    float* partial = (float*)d_ws;            // [32][32][2][64] f32 = 512 KB

    dim3 grid(TC, 2, BB);                     // 2048 blocks
    shapeconv_main<<<grid, 256, 0, stream>>>(x, w, partial);
    reduce_kernel<<<16, 256, 0, stream>>>(partial, out);
}